// Round 1
// baseline (619.481 us; speedup 1.0000x reference)
//
#include <hip/hip_runtime.h>
#include <stdint.h>

// Problem constants
#define T_TOK 4096
#define D_DIM 1024
#define H_DIM 2048
#define E_EXP 8
#define K_TOP 2
#define NTK   (T_TOK * K_TOP)   // 8192 (token, slot) pairs
#define MAX_TILES 80            // >= 8192/128 + 8

typedef short bf16x8 __attribute__((ext_vector_type(8)));
typedef float f32x4  __attribute__((ext_vector_type(4)));

#define MINI(a, b) ((a) < (b) ? (a) : (b))

__device__ __forceinline__ unsigned short f2bf(float f) {
  unsigned u = __float_as_uint(f);
  u += 0x7fffu + ((u >> 16) & 1u);   // round-to-nearest-even
  return (unsigned short)(u >> 16);
}

// async global->LDS, 16B per lane; lds base must be wave-uniform
#define GLDS16(gp, lp)                                                        \
  __builtin_amdgcn_global_load_lds(                                           \
      (const __attribute__((address_space(1))) void*)(gp),                    \
      (__attribute__((address_space(3))) void*)(lp), 16, 0, 0)

// meta layout (ints): [0..7] counts, [8..15] offsets, [16..23] cursors,
// [24] n_tiles, [32..111] tile_expert, [112..191] tile_row0, [192..271] tile_valid

__global__ __launch_bounds__(256) void k_route1(const int* __restrict__ idx,
                                                int* __restrict__ meta) {
  __shared__ int lc[E_EXP];
  int tid = threadIdx.x;
  if (tid < E_EXP) lc[tid] = 0;
  __syncthreads();
  for (int i = tid; i < NTK; i += 256) atomicAdd(&lc[idx[i] & (E_EXP - 1)], 1);
  __syncthreads();
  if (tid == 0) {
    int off = 0, nt = 0;
    for (int e = 0; e < E_EXP; ++e) {
      int c = lc[e];
      meta[0 + e]  = c;
      meta[8 + e]  = off;
      meta[16 + e] = off;  // cursor
      for (int r = 0; r < c; r += 128) {
        meta[32 + nt]  = e;
        meta[112 + nt] = off + r;
        meta[192 + nt] = MINI(128, c - r);
        ++nt;
      }
      off += c;
    }
    meta[24] = nt;
  }
}

__global__ __launch_bounds__(256) void k_route2(const int* __restrict__ idx,
                                                const float* __restrict__ w,
                                                int* __restrict__ meta,
                                                int* __restrict__ rows,
                                                float* __restrict__ wv) {
  int i = blockIdx.x * 256 + threadIdx.x;
  if (i < NTK) {
    int e = idx[i] & (E_EXP - 1);
    int p = atomicAdd(&meta[16 + e], 1);
    rows[p] = i >> 1;  // K_TOP = 2
    wv[p]   = w[i];
  }
}

__global__ __launch_bounds__(256) void k_cvt(const float* __restrict__ src,
                                             unsigned short* __restrict__ dst,
                                             int n4) {
  int i = blockIdx.x * 256 + threadIdx.x;
  if (i < n4) {
    float4 v = ((const float4*)src)[i];
    ushort4 o;
    o.x = f2bf(v.x); o.y = f2bf(v.y); o.z = f2bf(v.z); o.w = f2bf(v.w);
    ((ushort4*)dst)[i] = o;
  }
}

// GEMM1: h = Xg @ W1e^T (both strips), act = f2bf(u * silu(gate) * w_row)
// A: gathered x rows [128 x 1024], B: W1e rows (u strip + gate strip)
__global__ __launch_bounds__(256) void k_gemm1(
    const unsigned short* __restrict__ xb,   // [T][1024] bf16
    const unsigned short* __restrict__ W1b,  // [E][4096][1024] bf16
    const int* __restrict__ meta,
    const int* __restrict__ rows,
    const float* __restrict__ wv,
    unsigned short* __restrict__ act) {      // [8192][2048] bf16
  int nt = meta[24];
  int tb = blockIdx.x;
  if (tb >= nt) return;
  int e     = meta[32 + tb];
  int r0    = meta[112 + tb];
  int valid = meta[192 + tb];
  int n0    = blockIdx.y * 128;

  __shared__ unsigned short lA[128 * 32];
  __shared__ unsigned short lB1[128 * 32];
  __shared__ unsigned short lB2[128 * 32];
  __shared__ float sw[128];

  int tid = threadIdx.x;
  int wave = tid >> 6, lane = tid & 63;

  if (tid < 128) sw[tid] = wv[r0 + MINI(tid, valid - 1)];

  const unsigned short* w1e = W1b + (size_t)e * (4096 * 1024);

  const unsigned short* gA[2];
  const unsigned short* gB1[2];
  const unsigned short* gB2[2];
#pragma unroll
  for (int r = 0; r < 2; ++r) {
    int c = r * 256 + wave * 64 + lane;
    int row = c >> 2, cc = c & 3;
    int tok = rows[r0 + MINI(row, valid - 1)];
    gA[r]  = xb  + (size_t)tok * 1024 + cc * 8;
    gB1[r] = w1e + (size_t)(n0 + row) * 1024 + cc * 8;
    gB2[r] = w1e + (size_t)(2048 + n0 + row) * 1024 + cc * 8;
  }

  f32x4 zero = {0.f, 0.f, 0.f, 0.f};
  f32x4 au[4][4], ag[4][4];
#pragma unroll
  for (int i = 0; i < 4; ++i)
#pragma unroll
    for (int j = 0; j < 4; ++j) { au[i][j] = zero; ag[i][j] = zero; }

  int mb = (wave >> 1) * 64, nb = (wave & 1) * 64;
  int fr = lane & 15, q = lane >> 4;

  for (int k0 = 0; k0 < 1024; k0 += 32) {
    __syncthreads();
#pragma unroll
    for (int r = 0; r < 2; ++r) {
      int lbase = (r * 256 + wave * 64) * 8;  // ushort units (16B chunks)
      GLDS16(gA[r]  + k0, &lA[lbase]);
      GLDS16(gB1[r] + k0, &lB1[lbase]);
      GLDS16(gB2[r] + k0, &lB2[lbase]);
    }
    __syncthreads();
    bf16x8 a[4];
#pragma unroll
    for (int i = 0; i < 4; ++i)
      a[i] = *(const bf16x8*)&lA[(mb + i * 16 + fr) * 32 + q * 8];
#pragma unroll
    for (int j = 0; j < 4; ++j) {
      bf16x8 bu = *(const bf16x8*)&lB1[(nb + j * 16 + fr) * 32 + q * 8];
      bf16x8 bg = *(const bf16x8*)&lB2[(nb + j * 16 + fr) * 32 + q * 8];
#pragma unroll
      for (int i = 0; i < 4; ++i) {
        au[i][j] = __builtin_amdgcn_mfma_f32_16x16x32_bf16(a[i], bu, au[i][j], 0, 0, 0);
        ag[i][j] = __builtin_amdgcn_mfma_f32_16x16x32_bf16(a[i], bg, ag[i][j], 0, 0, 0);
      }
    }
  }

#pragma unroll
  for (int i = 0; i < 4; ++i) {
#pragma unroll
    for (int reg = 0; reg < 4; ++reg) {
      int lm = mb + i * 16 + q * 4 + reg;
      if (lm < valid) {
        float wrow = sw[lm];
        size_t orow = (size_t)(r0 + lm) * 2048;
#pragma unroll
        for (int j = 0; j < 4; ++j) {
          float u = au[i][j][reg];
          float g = ag[i][j][reg];
          float s = g / (1.f + __expf(-g));
          act[orow + (n0 + nb + j * 16 + fr)] = f2bf(u * s * wrow);
        }
      }
    }
  }
}

// GEMM2: out_slot = act @ W2e^T, atomicAdd into d_out (weight already applied)
__global__ __launch_bounds__(256) void k_gemm2(
    const unsigned short* __restrict__ act,  // [8192][2048] bf16
    const unsigned short* __restrict__ W2b,  // [E][1024][2048] bf16
    const int* __restrict__ meta,
    const int* __restrict__ rows,
    float* __restrict__ out) {               // [4096][1024] fp32
  int nt = meta[24];
  int tb = blockIdx.x;
  if (tb >= nt) return;
  int e     = meta[32 + tb];
  int r0    = meta[112 + tb];
  int valid = meta[192 + tb];
  int n0    = blockIdx.y * 128;

  __shared__ unsigned short lA[128 * 32];
  __shared__ unsigned short lB[128 * 32];
  __shared__ int st[128];

  int tid = threadIdx.x;
  int wave = tid >> 6, lane = tid & 63;
  if (tid < 128) st[tid] = rows[r0 + MINI(tid, valid - 1)];

  const unsigned short* w2e = W2b + (size_t)e * (1024 * 2048);

  const unsigned short* gA[2];
  const unsigned short* gB[2];
#pragma unroll
  for (int r = 0; r < 2; ++r) {
    int c = r * 256 + wave * 64 + lane;
    int row = c >> 2, cc = c & 3;
    gA[r] = act + (size_t)(r0 + MINI(row, valid - 1)) * 2048 + cc * 8;
    gB[r] = w2e + (size_t)(n0 + row) * 2048 + cc * 8;
  }

  f32x4 zero = {0.f, 0.f, 0.f, 0.f};
  f32x4 acc[4][4];
#pragma unroll
  for (int i = 0; i < 4; ++i)
#pragma unroll
    for (int j = 0; j < 4; ++j) acc[i][j] = zero;

  int mb = (wave >> 1) * 64, nb = (wave & 1) * 64;
  int fr = lane & 15, q = lane >> 4;

  for (int k0 = 0; k0 < 2048; k0 += 32) {
    __syncthreads();
#pragma unroll
    for (int r = 0; r < 2; ++r) {
      int lbase = (r * 256 + wave * 64) * 8;
      GLDS16(gA[r] + k0, &lA[lbase]);
      GLDS16(gB[r] + k0, &lB[lbase]);
    }
    __syncthreads();
    bf16x8 a[4];
#pragma unroll
    for (int i = 0; i < 4; ++i)
      a[i] = *(const bf16x8*)&lA[(mb + i * 16 + fr) * 32 + q * 8];
#pragma unroll
    for (int j = 0; j < 4; ++j) {
      bf16x8 b = *(const bf16x8*)&lB[(nb + j * 16 + fr) * 32 + q * 8];
#pragma unroll
      for (int i = 0; i < 4; ++i)
        acc[i][j] = __builtin_amdgcn_mfma_f32_16x16x32_bf16(a[i], b, acc[i][j], 0, 0, 0);
    }
  }

#pragma unroll
  for (int i = 0; i < 4; ++i) {
#pragma unroll
    for (int reg = 0; reg < 4; ++reg) {
      int lm = mb + i * 16 + q * 4 + reg;
      if (lm < valid) {
        int tok = st[lm];
        float* op = out + (size_t)tok * 1024;
#pragma unroll
        for (int j = 0; j < 4; ++j)
          atomicAdd(&op[n0 + nb + j * 16 + fr], acc[i][j][reg]);
      }
    }
  }
}

extern "C" void kernel_launch(void* const* d_in, const int* in_sizes, int n_in,
                              void* d_out, int out_size, void* d_ws, size_t ws_size,
                              hipStream_t stream) {
  const float* x  = (const float*)d_in[0];   // [T][D]
  const float* w  = (const float*)d_in[1];   // [T][K]
  const int*  idx = (const int*)d_in[2];     // [T][K]
  const float* W1 = (const float*)d_in[3];   // [E][2H][D]
  const float* W2 = (const float*)d_in[4];   // [E][D][H]
  float* out = (float*)d_out;

  char* ws = (char*)d_ws;
  unsigned short* W1b = (unsigned short*)(ws);              // 67108864 B
  unsigned short* W2b = (unsigned short*)(ws + 67108864);   // 33554432 B
  unsigned short* xb  = (unsigned short*)(ws + 100663296);  //  8388608 B
  unsigned short* act = (unsigned short*)(ws + 109051904);  // 33554432 B
  int*   rows = (int*)(ws + 142606336);                     //    32768 B
  float* wv   = (float*)(ws + 142639104);                   //    32768 B
  int*   meta = (int*)(ws + 142671872);                     //     1088 B

  hipMemsetAsync(d_out, 0, (size_t)out_size * sizeof(float), stream);

  k_route1<<<1, 256, 0, stream>>>(idx, meta);
  k_route2<<<(NTK + 255) / 256, 256, 0, stream>>>(idx, w, meta, rows, wv);

  k_cvt<<<(T_TOK * D_DIM / 4 + 255) / 256, 256, 0, stream>>>(x, xb, T_TOK * D_DIM / 4);
  k_cvt<<<(E_EXP * 2 * H_DIM * D_DIM / 4 + 255) / 256, 256, 0, stream>>>(W1, W1b, E_EXP * 2 * H_DIM * D_DIM / 4);
  k_cvt<<<(E_EXP * D_DIM * H_DIM / 4 + 255) / 256, 256, 0, stream>>>(W2, W2b, E_EXP * D_DIM * H_DIM / 4);

  dim3 g1(MAX_TILES, H_DIM / 128);  // (80, 16)
  dim3 g2(MAX_TILES, D_DIM / 128);  // (80, 8)
  k_gemm1<<<g1, 256, 0, stream>>>(xb, W1b, meta, rows, wv, act);
  k_gemm2<<<g2, 256, 0, stream>>>(act, W2b, meta, rows, out);
}

// Round 2
// 566.575 us; speedup vs baseline: 1.0934x; 1.0934x over previous
//
#include <hip/hip_runtime.h>
#include <stdint.h>

// Problem constants
#define T_TOK 4096
#define D_DIM 1024
#define H_DIM 2048
#define E_EXP 8
#define K_TOP 2
#define NTK   (T_TOK * K_TOP)   // 8192 (token, slot) pairs
#define MAX_TILES 80            // >= 8192/128 + 8

typedef short bf16x8 __attribute__((ext_vector_type(8)));
typedef float f32x4  __attribute__((ext_vector_type(4)));

#define MINI(a, b) ((a) < (b) ? (a) : (b))

__device__ __forceinline__ unsigned short f2bf(float f) {
  unsigned u = __float_as_uint(f);
  u += 0x7fffu + ((u >> 16) & 1u);   // round-to-nearest-even
  return (unsigned short)(u >> 16);
}

// async global->LDS, 16B per lane; lds base must be wave-uniform
#define GLDS16(gp, lp)                                                        \
  __builtin_amdgcn_global_load_lds(                                           \
      (const __attribute__((address_space(1))) void*)(gp),                    \
      (__attribute__((address_space(3))) void*)(lp), 16, 0, 0)

// meta layout (ints): [0..7] counts, [8..15] offsets, [16..23] cursors,
// [24] n_tiles, [32..111] tile_expert, [112..191] tile_row0, [192..271] tile_valid

__global__ __launch_bounds__(256) void k_route1(const int* __restrict__ idx,
                                                int* __restrict__ meta) {
  __shared__ int lc[E_EXP];
  int tid = threadIdx.x;
  if (tid < E_EXP) lc[tid] = 0;
  __syncthreads();
  for (int i = tid; i < NTK; i += 256) atomicAdd(&lc[idx[i] & (E_EXP - 1)], 1);
  __syncthreads();
  if (tid == 0) {
    int off = 0, nt = 0;
    for (int e = 0; e < E_EXP; ++e) {
      int c = lc[e];
      meta[0 + e]  = c;
      meta[8 + e]  = off;
      meta[16 + e] = off;  // cursor
      for (int r = 0; r < c; r += 128) {
        meta[32 + nt]  = e;
        meta[112 + nt] = off + r;
        meta[192 + nt] = MINI(128, c - r);
        ++nt;
      }
      off += c;
    }
    meta[24] = nt;
  }
}

__global__ __launch_bounds__(256) void k_route2(const int* __restrict__ idx,
                                                const float* __restrict__ w,
                                                int* __restrict__ meta,
                                                int* __restrict__ rows,
                                                float* __restrict__ wv) {
  int i = blockIdx.x * 256 + threadIdx.x;
  if (i < NTK) {
    int e = idx[i] & (E_EXP - 1);
    int p = atomicAdd(&meta[16 + e], 1);
    rows[p] = i >> 1;  // K_TOP = 2
    wv[p]   = w[i];
  }
}

__global__ __launch_bounds__(256) void k_cvt(const float* __restrict__ src,
                                             unsigned short* __restrict__ dst,
                                             int n4) {
  int i = blockIdx.x * 256 + threadIdx.x;
  if (i < n4) {
    float4 v = ((const float4*)src)[i];
    ushort4 o;
    o.x = f2bf(v.x); o.y = f2bf(v.y); o.z = f2bf(v.z); o.w = f2bf(v.w);
    ((ushort4*)dst)[i] = o;
  }
}

// GEMM1: h = Xg @ W1e^T (both strips), act = f2bf(u * silu(gate) * w_row)
// BK=64, LDS rows of 128B; global-source XOR swizzle: LDS chunk (r,c) holds
// global chunk c^(r&7) -> bank-conflict-free b128 reads (2-way only).
__global__ __launch_bounds__(256) void k_gemm1(
    const unsigned short* __restrict__ xb,   // [T][1024] bf16
    const unsigned short* __restrict__ W1b,  // [E][4096][1024] bf16
    const int* __restrict__ meta,
    const int* __restrict__ rows,
    const float* __restrict__ wv,
    unsigned short* __restrict__ act) {      // [8192][2048] bf16
  int nt = meta[24];
  int tb = blockIdx.x;
  if (tb >= nt) return;
  int e     = meta[32 + tb];
  int r0    = meta[112 + tb];
  int valid = meta[192 + tb];
  int n0    = blockIdx.y * 128;

  __shared__ unsigned short lA[128 * 64];
  __shared__ unsigned short lB1[128 * 64];
  __shared__ unsigned short lB2[128 * 64];
  __shared__ float sw[128];

  int tid = threadIdx.x;
  int wave = tid >> 6, lane = tid & 63;

  if (tid < 128) sw[tid] = wv[r0 + MINI(tid, valid - 1)];

  const unsigned short* w1e = W1b + (size_t)e * (4096 * 1024);

  // staging pointers: thread covers LDS linear chunk c = it*256+tid
  const unsigned short *pA[4], *pB1[4], *pB2[4];
#pragma unroll
  for (int it = 0; it < 4; ++it) {
    int c = it * 256 + tid;
    int r = c >> 3, cc = c & 7;
    int g = cc ^ (r & 7);                  // swizzled global chunk
    int tok = rows[r0 + MINI(r, valid - 1)];
    pA[it]  = xb  + (size_t)tok * 1024 + g * 8;
    pB1[it] = w1e + (size_t)(n0 + r) * 1024 + g * 8;
    pB2[it] = w1e + (size_t)(2048 + n0 + r) * 1024 + g * 8;
  }

  f32x4 zero = {0.f, 0.f, 0.f, 0.f};
  f32x4 au[4][4], ag[4][4];
#pragma unroll
  for (int i = 0; i < 4; ++i)
#pragma unroll
    for (int j = 0; j < 4; ++j) { au[i][j] = zero; ag[i][j] = zero; }

  int mb = (wave >> 1) * 64, nb = (wave & 1) * 64;
  int fr = lane & 15, q = lane >> 4;

  for (int k0 = 0; k0 < 1024; k0 += 64) {
    __syncthreads();
#pragma unroll
    for (int it = 0; it < 4; ++it) {
      int lb = (it * 256 + wave * 64) * 8;  // ushort units
      GLDS16(pA[it]  + k0, &lA[lb]);
      GLDS16(pB1[it] + k0, &lB1[lb]);
      GLDS16(pB2[it] + k0, &lB2[lb]);
    }
    __syncthreads();
#pragma unroll
    for (int kk = 0; kk < 2; ++kk) {
      int co = (((kk << 2) + q) ^ (fr & 7)) * 8 + fr * 64;  // swizzled read
      bf16x8 a[4];
#pragma unroll
      for (int i = 0; i < 4; ++i)
        a[i] = *(const bf16x8*)&lA[(mb + i * 16) * 64 + co];
#pragma unroll
      for (int j = 0; j < 4; ++j) {
        bf16x8 bu = *(const bf16x8*)&lB1[(nb + j * 16) * 64 + co];
        bf16x8 bg = *(const bf16x8*)&lB2[(nb + j * 16) * 64 + co];
#pragma unroll
        for (int i = 0; i < 4; ++i) {
          au[i][j] = __builtin_amdgcn_mfma_f32_16x16x32_bf16(a[i], bu, au[i][j], 0, 0, 0);
          ag[i][j] = __builtin_amdgcn_mfma_f32_16x16x32_bf16(a[i], bg, ag[i][j], 0, 0, 0);
        }
      }
    }
  }

#pragma unroll
  for (int i = 0; i < 4; ++i) {
#pragma unroll
    for (int reg = 0; reg < 4; ++reg) {
      int lm = mb + i * 16 + q * 4 + reg;
      if (lm < valid) {
        float wrow = sw[lm];
        size_t orow = (size_t)(r0 + lm) * 2048;
#pragma unroll
        for (int j = 0; j < 4; ++j) {
          float u = au[i][j][reg];
          float g = ag[i][j][reg];
          float s = g / (1.f + __expf(-g));
          act[orow + (n0 + nb + j * 16 + fr)] = f2bf(u * s * wrow);
        }
      }
    }
  }
}

// GEMM2: out_slot = act @ W2e^T, atomicAdd into d_out (weight already applied)
// BK=64 + same XOR swizzle.
__global__ __launch_bounds__(256) void k_gemm2(
    const unsigned short* __restrict__ act,  // [8192][2048] bf16
    const unsigned short* __restrict__ W2b,  // [E][1024][2048] bf16
    const int* __restrict__ meta,
    const int* __restrict__ rows,
    float* __restrict__ out) {               // [4096][1024] fp32
  int nt = meta[24];
  int tb = blockIdx.x;
  if (tb >= nt) return;
  int e     = meta[32 + tb];
  int r0    = meta[112 + tb];
  int valid = meta[192 + tb];
  int n0    = blockIdx.y * 128;

  __shared__ unsigned short lA[128 * 64];
  __shared__ unsigned short lB[128 * 64];
  __shared__ int st[128];

  int tid = threadIdx.x;
  int wave = tid >> 6, lane = tid & 63;
  if (tid < 128) st[tid] = rows[r0 + MINI(tid, valid - 1)];

  const unsigned short* w2e = W2b + (size_t)e * (1024 * 2048);

  const unsigned short *pA[4], *pB[4];
#pragma unroll
  for (int it = 0; it < 4; ++it) {
    int c = it * 256 + tid;
    int r = c >> 3, cc = c & 7;
    int g = cc ^ (r & 7);
    pA[it] = act + (size_t)(r0 + MINI(r, valid - 1)) * 2048 + g * 8;
    pB[it] = w2e + (size_t)(n0 + r) * 2048 + g * 8;
  }

  f32x4 zero = {0.f, 0.f, 0.f, 0.f};
  f32x4 acc[4][4];
#pragma unroll
  for (int i = 0; i < 4; ++i)
#pragma unroll
    for (int j = 0; j < 4; ++j) acc[i][j] = zero;

  int mb = (wave >> 1) * 64, nb = (wave & 1) * 64;
  int fr = lane & 15, q = lane >> 4;

  for (int k0 = 0; k0 < 2048; k0 += 64) {
    __syncthreads();
#pragma unroll
    for (int it = 0; it < 4; ++it) {
      int lb = (it * 256 + wave * 64) * 8;
      GLDS16(pA[it] + k0, &lA[lb]);
      GLDS16(pB[it] + k0, &lB[lb]);
    }
    __syncthreads();
#pragma unroll
    for (int kk = 0; kk < 2; ++kk) {
      int co = (((kk << 2) + q) ^ (fr & 7)) * 8 + fr * 64;
      bf16x8 a[4];
#pragma unroll
      for (int i = 0; i < 4; ++i)
        a[i] = *(const bf16x8*)&lA[(mb + i * 16) * 64 + co];
#pragma unroll
      for (int j = 0; j < 4; ++j) {
        bf16x8 b = *(const bf16x8*)&lB[(nb + j * 16) * 64 + co];
#pragma unroll
        for (int i = 0; i < 4; ++i)
          acc[i][j] = __builtin_amdgcn_mfma_f32_16x16x32_bf16(a[i], b, acc[i][j], 0, 0, 0);
      }
    }
  }

#pragma unroll
  for (int i = 0; i < 4; ++i) {
#pragma unroll
    for (int reg = 0; reg < 4; ++reg) {
      int lm = mb + i * 16 + q * 4 + reg;
      if (lm < valid) {
        int tok = st[lm];
        float* op = out + (size_t)tok * 1024;
#pragma unroll
        for (int j = 0; j < 4; ++j)
          atomicAdd(&op[n0 + nb + j * 16 + fr], acc[i][j][reg]);
      }
    }
  }
}

extern "C" void kernel_launch(void* const* d_in, const int* in_sizes, int n_in,
                              void* d_out, int out_size, void* d_ws, size_t ws_size,
                              hipStream_t stream) {
  const float* x  = (const float*)d_in[0];   // [T][D]
  const float* w  = (const float*)d_in[1];   // [T][K]
  const int*  idx = (const int*)d_in[2];     // [T][K]
  const float* W1 = (const float*)d_in[3];   // [E][2H][D]
  const float* W2 = (const float*)d_in[4];   // [E][D][H]
  float* out = (float*)d_out;

  char* ws = (char*)d_ws;
  unsigned short* W1b = (unsigned short*)(ws);              // 67108864 B
  unsigned short* W2b = (unsigned short*)(ws + 67108864);   // 33554432 B
  unsigned short* xb  = (unsigned short*)(ws + 100663296);  //  8388608 B
  unsigned short* act = (unsigned short*)(ws + 109051904);  // 33554432 B
  int*   rows = (int*)(ws + 142606336);                     //    32768 B
  float* wv   = (float*)(ws + 142639104);                   //    32768 B
  int*   meta = (int*)(ws + 142671872);                     //     1088 B

  hipMemsetAsync(d_out, 0, (size_t)out_size * sizeof(float), stream);

  k_route1<<<1, 256, 0, stream>>>(idx, meta);
  k_route2<<<(NTK + 255) / 256, 256, 0, stream>>>(idx, w, meta, rows, wv);

  k_cvt<<<(T_TOK * D_DIM / 4 + 255) / 256, 256, 0, stream>>>(x, xb, T_TOK * D_DIM / 4);
  k_cvt<<<(E_EXP * 2 * H_DIM * D_DIM / 4 + 255) / 256, 256, 0, stream>>>(W1, W1b, E_EXP * 2 * H_DIM * D_DIM / 4);
  k_cvt<<<(E_EXP * D_DIM * H_DIM / 4 + 255) / 256, 256, 0, stream>>>(W2, W2b, E_EXP * D_DIM * H_DIM / 4);

  dim3 g1(MAX_TILES, H_DIM / 128);  // (80, 16)
  dim3 g2(MAX_TILES, D_DIM / 128);  // (80, 8)
  k_gemm1<<<g1, 256, 0, stream>>>(xb, W1b, meta, rows, wv, act);
  k_gemm2<<<g2, 256, 0, stream>>>(act, W2b, meta, rows, out);
}

// Round 3
// 501.066 us; speedup vs baseline: 1.2363x; 1.1307x over previous
//
#include <hip/hip_runtime.h>
#include <stdint.h>

// Problem constants
#define T_TOK 4096
#define D_DIM 1024
#define H_DIM 2048
#define E_EXP 8
#define K_TOP 2
#define NTK   (T_TOK * K_TOP)   // 8192 (token, slot) pairs
#define MAX_TILES 80            // >= 8192/128 + 8

typedef short bf16x8 __attribute__((ext_vector_type(8)));
typedef float f32x4  __attribute__((ext_vector_type(4)));

#define MINI(a, b) ((a) < (b) ? (a) : (b))

__device__ __forceinline__ unsigned short f2bf(float f) {
  unsigned u = __float_as_uint(f);
  u += 0x7fffu + ((u >> 16) & 1u);   // round-to-nearest-even
  return (unsigned short)(u >> 16);
}

// async global->LDS, 16B per lane; lds base must be wave-uniform
#define GLDS16(gp, lp)                                                        \
  __builtin_amdgcn_global_load_lds(                                           \
      (const __attribute__((address_space(1))) void*)(gp),                    \
      (__attribute__((address_space(3))) void*)(lp), 16, 0, 0)

// meta layout (ints): [0..7] counts, [8..15] offsets, [16..23] cursors,
// [24] n_tiles, [32..111] tile_expert, [112..191] tile_row0, [192..271] tile_valid

__global__ __launch_bounds__(256) void k_route1(const int* __restrict__ idx,
                                                int* __restrict__ meta) {
  __shared__ int lc[E_EXP];
  int tid = threadIdx.x;
  if (tid < E_EXP) lc[tid] = 0;
  __syncthreads();
  for (int i = tid; i < NTK; i += 256) atomicAdd(&lc[idx[i] & (E_EXP - 1)], 1);
  __syncthreads();
  if (tid == 0) {
    int off = 0, nt = 0;
    for (int e = 0; e < E_EXP; ++e) {
      int c = lc[e];
      meta[0 + e]  = c;
      meta[8 + e]  = off;
      meta[16 + e] = off;  // cursor
      for (int r = 0; r < c; r += 128) {
        meta[32 + nt]  = e;
        meta[112 + nt] = off + r;
        meta[192 + nt] = MINI(128, c - r);
        ++nt;
      }
      off += c;
    }
    meta[24] = nt;
  }
}

__global__ __launch_bounds__(256) void k_route2(const int* __restrict__ idx,
                                                const float* __restrict__ w,
                                                int* __restrict__ meta,
                                                int* __restrict__ rows,
                                                float* __restrict__ wv) {
  int i = blockIdx.x * 256 + threadIdx.x;
  if (i < NTK) {
    int e = idx[i] & (E_EXP - 1);
    int p = atomicAdd(&meta[16 + e], 1);
    rows[p] = i >> 1;  // K_TOP = 2
    wv[p]   = w[i];
  }
}

__global__ __launch_bounds__(256) void k_cvt(const float* __restrict__ src,
                                             unsigned short* __restrict__ dst,
                                             int n4) {
  int i = blockIdx.x * 256 + threadIdx.x;
  if (i < n4) {
    float4 v = ((const float4*)src)[i];
    ushort4 o;
    o.x = f2bf(v.x); o.y = f2bf(v.y); o.z = f2bf(v.z); o.w = f2bf(v.w);
    ((ushort4*)dst)[i] = o;
  }
}

// GEMM1: h = Xg @ W1e^T (both strips), act = f2bf(u * silu(gate) * w_row)
// Block tile: M=128 rows x 64 act-cols (64 u-rows + 64 gate-rows of W1).
// Wave tile: 32 rows x 64 cols x both strips -> acc = 16 f32x4 = 64 AGPRs,
// keeping total regs <= 256 so 2 waves/SIMD (2 blocks/CU) are resident.
// BK=64; XOR source swizzle keeps ds_read_b128 conflict-free.
__global__ __launch_bounds__(256, 2) void k_gemm1(
    const unsigned short* __restrict__ xb,   // [T][1024] bf16
    const unsigned short* __restrict__ W1b,  // [E][4096][1024] bf16
    const int* __restrict__ meta,
    const int* __restrict__ rows,
    const float* __restrict__ wv,
    unsigned short* __restrict__ act) {      // [8192][2048] bf16
  int nt = meta[24];
  int tb = blockIdx.x;
  if (tb >= nt) return;
  int e     = meta[32 + tb];
  int r0    = meta[112 + tb];
  int valid = meta[192 + tb];
  int n0    = blockIdx.y * 64;

  __shared__ unsigned short lA[128 * 64];   // 16 KB
  __shared__ unsigned short lB1[64 * 64];   //  8 KB
  __shared__ unsigned short lB2[64 * 64];   //  8 KB
  __shared__ float sw[128];

  int tid = threadIdx.x;
  int wave = tid >> 6, lane = tid & 63;

  if (tid < 128) sw[tid] = wv[r0 + MINI(tid, valid - 1)];

  const unsigned short* w1e = W1b + (size_t)e * (4096 * 1024);

  // staging: A covers chunks [0,1024), B strips [0,512) each
  const unsigned short *pA[4], *pB1[2], *pB2[2];
#pragma unroll
  for (int it = 0; it < 4; ++it) {
    int c = it * 256 + tid;
    int r = c >> 3, cc = c & 7;
    int g = cc ^ (r & 7);
    int tok = rows[r0 + MINI(r, valid - 1)];
    pA[it] = xb + (size_t)tok * 1024 + g * 8;
  }
#pragma unroll
  for (int it = 0; it < 2; ++it) {
    int c = it * 256 + tid;
    int r = c >> 3, cc = c & 7;
    int g = cc ^ (r & 7);
    pB1[it] = w1e + (size_t)(n0 + r) * 1024 + g * 8;
    pB2[it] = w1e + (size_t)(2048 + n0 + r) * 1024 + g * 8;
  }

  f32x4 zero = {0.f, 0.f, 0.f, 0.f};
  f32x4 au[2][4], ag[2][4];
#pragma unroll
  for (int i = 0; i < 2; ++i)
#pragma unroll
    for (int j = 0; j < 4; ++j) { au[i][j] = zero; ag[i][j] = zero; }

  int mb = wave * 32;
  int fr = lane & 15, q = lane >> 4;

  for (int k0 = 0; k0 < 1024; k0 += 64) {
    __syncthreads();
#pragma unroll
    for (int it = 0; it < 4; ++it)
      GLDS16(pA[it] + k0, &lA[(it * 256 + wave * 64) * 8]);
#pragma unroll
    for (int it = 0; it < 2; ++it) {
      int lb = (it * 256 + wave * 64) * 8;
      GLDS16(pB1[it] + k0, &lB1[lb]);
      GLDS16(pB2[it] + k0, &lB2[lb]);
    }
    __syncthreads();
#pragma unroll
    for (int kk = 0; kk < 2; ++kk) {
      int co = (((kk << 2) + q) ^ (fr & 7)) * 8 + fr * 64;  // swizzled read
      bf16x8 a[2];
#pragma unroll
      for (int i = 0; i < 2; ++i)
        a[i] = *(const bf16x8*)&lA[(mb + i * 16) * 64 + co];
#pragma unroll
      for (int j = 0; j < 4; ++j) {
        bf16x8 bu = *(const bf16x8*)&lB1[(j * 16) * 64 + co];
        bf16x8 bg = *(const bf16x8*)&lB2[(j * 16) * 64 + co];
#pragma unroll
        for (int i = 0; i < 2; ++i) {
          au[i][j] = __builtin_amdgcn_mfma_f32_16x16x32_bf16(a[i], bu, au[i][j], 0, 0, 0);
          ag[i][j] = __builtin_amdgcn_mfma_f32_16x16x32_bf16(a[i], bg, ag[i][j], 0, 0, 0);
        }
      }
    }
  }

#pragma unroll
  for (int i = 0; i < 2; ++i) {
#pragma unroll
    for (int reg = 0; reg < 4; ++reg) {
      int lm = mb + i * 16 + q * 4 + reg;
      if (lm < valid) {
        float wrow = sw[lm];
        size_t orow = (size_t)(r0 + lm) * 2048;
#pragma unroll
        for (int j = 0; j < 4; ++j) {
          float u = au[i][j][reg];
          float g = ag[i][j][reg];
          float s = g / (1.f + __expf(-g));
          act[orow + (n0 + j * 16 + fr)] = f2bf(u * s * wrow);
        }
      }
    }
  }
}

// GEMM2: out_slot = act @ W2e^T, atomicAdd into d_out (weight already applied)
// BK=64 + same XOR swizzle. (228 regs -> already 2 waves/SIMD.)
__global__ __launch_bounds__(256) void k_gemm2(
    const unsigned short* __restrict__ act,  // [8192][2048] bf16
    const unsigned short* __restrict__ W2b,  // [E][1024][2048] bf16
    const int* __restrict__ meta,
    const int* __restrict__ rows,
    float* __restrict__ out) {               // [4096][1024] fp32
  int nt = meta[24];
  int tb = blockIdx.x;
  if (tb >= nt) return;
  int e     = meta[32 + tb];
  int r0    = meta[112 + tb];
  int valid = meta[192 + tb];
  int n0    = blockIdx.y * 128;

  __shared__ unsigned short lA[128 * 64];
  __shared__ unsigned short lB[128 * 64];
  __shared__ int st[128];

  int tid = threadIdx.x;
  int wave = tid >> 6, lane = tid & 63;
  if (tid < 128) st[tid] = rows[r0 + MINI(tid, valid - 1)];

  const unsigned short* w2e = W2b + (size_t)e * (1024 * 2048);

  const unsigned short *pA[4], *pB[4];
#pragma unroll
  for (int it = 0; it < 4; ++it) {
    int c = it * 256 + tid;
    int r = c >> 3, cc = c & 7;
    int g = cc ^ (r & 7);
    pA[it] = act + (size_t)(r0 + MINI(r, valid - 1)) * 2048 + g * 8;
    pB[it] = w2e + (size_t)(n0 + r) * 2048 + g * 8;
  }

  f32x4 zero = {0.f, 0.f, 0.f, 0.f};
  f32x4 acc[4][4];
#pragma unroll
  for (int i = 0; i < 4; ++i)
#pragma unroll
    for (int j = 0; j < 4; ++j) acc[i][j] = zero;

  int mb = (wave >> 1) * 64, nb = (wave & 1) * 64;
  int fr = lane & 15, q = lane >> 4;

  for (int k0 = 0; k0 < 2048; k0 += 64) {
    __syncthreads();
#pragma unroll
    for (int it = 0; it < 4; ++it) {
      int lb = (it * 256 + wave * 64) * 8;
      GLDS16(pA[it] + k0, &lA[lb]);
      GLDS16(pB[it] + k0, &lB[lb]);
    }
    __syncthreads();
#pragma unroll
    for (int kk = 0; kk < 2; ++kk) {
      int co = (((kk << 2) + q) ^ (fr & 7)) * 8 + fr * 64;
      bf16x8 a[4];
#pragma unroll
      for (int i = 0; i < 4; ++i)
        a[i] = *(const bf16x8*)&lA[(mb + i * 16) * 64 + co];
#pragma unroll
      for (int j = 0; j < 4; ++j) {
        bf16x8 b = *(const bf16x8*)&lB[(nb + j * 16) * 64 + co];
#pragma unroll
        for (int i = 0; i < 4; ++i)
          acc[i][j] = __builtin_amdgcn_mfma_f32_16x16x32_bf16(a[i], b, acc[i][j], 0, 0, 0);
      }
    }
  }

#pragma unroll
  for (int i = 0; i < 4; ++i) {
#pragma unroll
    for (int reg = 0; reg < 4; ++reg) {
      int lm = mb + i * 16 + q * 4 + reg;
      if (lm < valid) {
        int tok = st[lm];
        float* op = out + (size_t)tok * 1024;
#pragma unroll
        for (int j = 0; j < 4; ++j)
          atomicAdd(&op[n0 + nb + j * 16 + fr], acc[i][j][reg]);
      }
    }
  }
}

extern "C" void kernel_launch(void* const* d_in, const int* in_sizes, int n_in,
                              void* d_out, int out_size, void* d_ws, size_t ws_size,
                              hipStream_t stream) {
  const float* x  = (const float*)d_in[0];   // [T][D]
  const float* w  = (const float*)d_in[1];   // [T][K]
  const int*  idx = (const int*)d_in[2];     // [T][K]
  const float* W1 = (const float*)d_in[3];   // [E][2H][D]
  const float* W2 = (const float*)d_in[4];   // [E][D][H]
  float* out = (float*)d_out;

  char* ws = (char*)d_ws;
  unsigned short* W1b = (unsigned short*)(ws);              // 67108864 B
  unsigned short* W2b = (unsigned short*)(ws + 67108864);   // 33554432 B
  unsigned short* xb  = (unsigned short*)(ws + 100663296);  //  8388608 B
  unsigned short* act = (unsigned short*)(ws + 109051904);  // 33554432 B
  int*   rows = (int*)(ws + 142606336);                     //    32768 B
  float* wv   = (float*)(ws + 142639104);                   //    32768 B
  int*   meta = (int*)(ws + 142671872);                     //     1088 B

  hipMemsetAsync(d_out, 0, (size_t)out_size * sizeof(float), stream);

  k_route1<<<1, 256, 0, stream>>>(idx, meta);
  k_route2<<<(NTK + 255) / 256, 256, 0, stream>>>(idx, w, meta, rows, wv);

  k_cvt<<<(T_TOK * D_DIM / 4 + 255) / 256, 256, 0, stream>>>(x, xb, T_TOK * D_DIM / 4);
  k_cvt<<<(E_EXP * 2 * H_DIM * D_DIM / 4 + 255) / 256, 256, 0, stream>>>(W1, W1b, E_EXP * 2 * H_DIM * D_DIM / 4);
  k_cvt<<<(E_EXP * D_DIM * H_DIM / 4 + 255) / 256, 256, 0, stream>>>(W2, W2b, E_EXP * D_DIM * H_DIM / 4);

  dim3 g1(MAX_TILES, H_DIM / 64);   // (80, 32)
  dim3 g2(MAX_TILES, D_DIM / 128);  // (80, 8)
  k_gemm1<<<g1, 256, 0, stream>>>(xb, W1b, meta, rows, wv, act);
  k_gemm2<<<g2, 256, 0, stream>>>(act, W2b, meta, rows, out);
}

// Round 4
// 498.129 us; speedup vs baseline: 1.2436x; 1.0059x over previous
//
#include <hip/hip_runtime.h>
#include <stdint.h>

// Problem constants
#define T_TOK 4096
#define D_DIM 1024
#define H_DIM 2048
#define E_EXP 8
#define K_TOP 2
#define NTK   (T_TOK * K_TOP)   // 8192 (token, slot) pairs
#define MAX_TILES 80            // >= 8192/128 + 8

typedef short bf16x8 __attribute__((ext_vector_type(8)));
typedef float f32x4  __attribute__((ext_vector_type(4)));

#define MINI(a, b) ((a) < (b) ? (a) : (b))

__device__ __forceinline__ unsigned short f2bf(float f) {
  unsigned u = __float_as_uint(f);
  u += 0x7fffu + ((u >> 16) & 1u);   // round-to-nearest-even
  return (unsigned short)(u >> 16);
}

// async global->LDS, 16B per lane; lds base must be wave-uniform
#define GLDS16(gp, lp)                                                        \
  __builtin_amdgcn_global_load_lds(                                           \
      (const __attribute__((address_space(1))) void*)(gp),                    \
      (__attribute__((address_space(3))) void*)(lp), 16, 0, 0)

// meta layout (ints): [0..7] counts, [8..15] offsets, [16..23] cursors,
// [24] n_tiles, [32..111] tile_expert, [112..191] tile_row0, [192..271] tile_valid

__global__ __launch_bounds__(256) void k_route1(const int* __restrict__ idx,
                                                int* __restrict__ meta) {
  __shared__ int lc[E_EXP];
  int tid = threadIdx.x;
  if (tid < E_EXP) lc[tid] = 0;
  __syncthreads();
  for (int i = tid; i < NTK; i += 256) atomicAdd(&lc[idx[i] & (E_EXP - 1)], 1);
  __syncthreads();
  if (tid == 0) {
    int off = 0, nt = 0;
    for (int e = 0; e < E_EXP; ++e) {
      int c = lc[e];
      meta[0 + e]  = c;
      meta[8 + e]  = off;
      meta[16 + e] = off;  // cursor
      for (int r = 0; r < c; r += 128) {
        meta[32 + nt]  = e;
        meta[112 + nt] = off + r;
        meta[192 + nt] = MINI(128, c - r);
        ++nt;
      }
      off += c;
    }
    meta[24] = nt;
  }
}

__global__ __launch_bounds__(256) void k_route2(const int* __restrict__ idx,
                                                const float* __restrict__ w,
                                                int* __restrict__ meta,
                                                int* __restrict__ rows,
                                                float* __restrict__ wv) {
  int i = blockIdx.x * 256 + threadIdx.x;
  if (i < NTK) {
    int e = idx[i] & (E_EXP - 1);
    int p = atomicAdd(&meta[16 + e], 1);
    rows[p] = i >> 1;  // K_TOP = 2
    wv[p]   = w[i];
  }
}

__global__ __launch_bounds__(256) void k_cvt(const float* __restrict__ src,
                                             unsigned short* __restrict__ dst,
                                             int n4) {
  int i = blockIdx.x * 256 + threadIdx.x;
  if (i < n4) {
    float4 v = ((const float4*)src)[i];
    ushort4 o;
    o.x = f2bf(v.x); o.y = f2bf(v.y); o.z = f2bf(v.z); o.w = f2bf(v.w);
    ((ushort4*)dst)[i] = o;
  }
}

// GEMM1: h = Xg @ W1e^T (both strips), act = f2bf(u * silu(gate) * w_row)
// Block: 128 threads (2 waves), tile M=128 rows x 64 act-cols (u+gate strips).
// Wave tile: 64 rows x 128 N -> acc = 32 f32x4 = 128 AGPR; + ~80 arch regs
// stays <=256 unified -> 2 waves/SIMD; LDS 32KB -> 4 blocks/CU, cross-block
// overlap hides barrier drains. BK=64; XOR source swizzle, conflict-free.
__global__ __launch_bounds__(128, 2) void k_gemm1(
    const unsigned short* __restrict__ xb,   // [T][1024] bf16
    const unsigned short* __restrict__ W1b,  // [E][4096][1024] bf16
    const int* __restrict__ meta,
    const int* __restrict__ rows,
    const float* __restrict__ wv,
    unsigned short* __restrict__ act) {      // [8192][2048] bf16
  int nt = meta[24];
  int tb = blockIdx.x;
  if (tb >= nt) return;
  int e     = meta[32 + tb];
  int r0    = meta[112 + tb];
  int valid = meta[192 + tb];
  int n0    = blockIdx.y * 64;

  __shared__ unsigned short lA[128 * 64];   // 16 KB
  __shared__ unsigned short lB1[64 * 64];   //  8 KB
  __shared__ unsigned short lB2[64 * 64];   //  8 KB
  __shared__ float sw[128];

  int tid = threadIdx.x;
  int wave = tid >> 6, lane = tid & 63;

  sw[tid] = wv[r0 + MINI(tid, valid - 1)];

  const unsigned short* w1e = W1b + (size_t)e * (4096 * 1024);

  // staging pointers: A = 1024 chunks over 128 threads (8 each), B strips 4 each
  const unsigned short *pA[8], *pB1[4], *pB2[4];
#pragma unroll
  for (int it = 0; it < 8; ++it) {
    int c = it * 128 + tid;
    int r = c >> 3, cc = c & 7;
    int g = cc ^ (r & 7);
    int tok = rows[r0 + MINI(r, valid - 1)];
    pA[it] = xb + (size_t)tok * 1024 + g * 8;
  }
#pragma unroll
  for (int it = 0; it < 4; ++it) {
    int c = it * 128 + tid;
    int r = c >> 3, cc = c & 7;
    int g = cc ^ (r & 7);
    pB1[it] = w1e + (size_t)(n0 + r) * 1024 + g * 8;
    pB2[it] = w1e + (size_t)(2048 + n0 + r) * 1024 + g * 8;
  }

  f32x4 zero = {0.f, 0.f, 0.f, 0.f};
  f32x4 au[4][4], ag[4][4];
#pragma unroll
  for (int i = 0; i < 4; ++i)
#pragma unroll
    for (int j = 0; j < 4; ++j) { au[i][j] = zero; ag[i][j] = zero; }

  int mb = wave * 64;
  int fr = lane & 15, q = lane >> 4;

  for (int k0 = 0; k0 < 1024; k0 += 64) {
    __syncthreads();
#pragma unroll
    for (int it = 0; it < 8; ++it)
      GLDS16(pA[it] + k0, &lA[(it * 128 + wave * 64) * 8]);
#pragma unroll
    for (int it = 0; it < 4; ++it) {
      int lb = (it * 128 + wave * 64) * 8;
      GLDS16(pB1[it] + k0, &lB1[lb]);
      GLDS16(pB2[it] + k0, &lB2[lb]);
    }
    __syncthreads();
#pragma unroll
    for (int kk = 0; kk < 2; ++kk) {
      int co = (((kk << 2) + q) ^ (fr & 7)) * 8 + fr * 64;  // swizzled read
      bf16x8 a[4];
#pragma unroll
      for (int i = 0; i < 4; ++i)
        a[i] = *(const bf16x8*)&lA[(mb + i * 16) * 64 + co];
#pragma unroll
      for (int j = 0; j < 4; ++j) {
        bf16x8 bu = *(const bf16x8*)&lB1[(j * 16) * 64 + co];
        bf16x8 bg = *(const bf16x8*)&lB2[(j * 16) * 64 + co];
#pragma unroll
        for (int i = 0; i < 4; ++i) {
          au[i][j] = __builtin_amdgcn_mfma_f32_16x16x32_bf16(a[i], bu, au[i][j], 0, 0, 0);
          ag[i][j] = __builtin_amdgcn_mfma_f32_16x16x32_bf16(a[i], bg, ag[i][j], 0, 0, 0);
        }
      }
    }
  }

#pragma unroll
  for (int i = 0; i < 4; ++i) {
#pragma unroll
    for (int reg = 0; reg < 4; ++reg) {
      int lm = mb + i * 16 + q * 4 + reg;
      if (lm < valid) {
        float wrow = sw[lm];
        size_t orow = (size_t)(r0 + lm) * 2048;
#pragma unroll
        for (int j = 0; j < 4; ++j) {
          float u = au[i][j][reg];
          float g = ag[i][j][reg];
          float s = g / (1.f + __expf(-g));
          act[orow + (n0 + j * 16 + fr)] = f2bf(u * s * wrow);
        }
      }
    }
  }
}

// GEMM2: out_slot = act @ W2e^T, atomicAdd into d_out (weight already applied)
// Same structure: 128 threads, block 128x128, wave tile 64x128, BK=64 + swizzle.
__global__ __launch_bounds__(128, 2) void k_gemm2(
    const unsigned short* __restrict__ act,  // [8192][2048] bf16
    const unsigned short* __restrict__ W2b,  // [E][1024][2048] bf16
    const int* __restrict__ meta,
    const int* __restrict__ rows,
    float* __restrict__ out) {               // [4096][1024] fp32
  int nt = meta[24];
  int tb = blockIdx.x;
  if (tb >= nt) return;
  int e     = meta[32 + tb];
  int r0    = meta[112 + tb];
  int valid = meta[192 + tb];
  int n0    = blockIdx.y * 128;

  __shared__ unsigned short lA[128 * 64];   // 16 KB
  __shared__ unsigned short lB[128 * 64];   // 16 KB
  __shared__ int st[128];

  int tid = threadIdx.x;
  int wave = tid >> 6, lane = tid & 63;
  st[tid] = rows[r0 + MINI(tid, valid - 1)];

  const unsigned short* w2e = W2b + (size_t)e * (1024 * 2048);

  const unsigned short *pA[8], *pB[8];
#pragma unroll
  for (int it = 0; it < 8; ++it) {
    int c = it * 128 + tid;
    int r = c >> 3, cc = c & 7;
    int g = cc ^ (r & 7);
    pA[it] = act + (size_t)(r0 + MINI(r, valid - 1)) * 2048 + g * 8;
    pB[it] = w2e + (size_t)(n0 + r) * 2048 + g * 8;
  }

  f32x4 zero = {0.f, 0.f, 0.f, 0.f};
  f32x4 acc[4][8];
#pragma unroll
  for (int i = 0; i < 4; ++i)
#pragma unroll
    for (int j = 0; j < 8; ++j) acc[i][j] = zero;

  int mb = wave * 64;
  int fr = lane & 15, q = lane >> 4;

  for (int k0 = 0; k0 < 2048; k0 += 64) {
    __syncthreads();
#pragma unroll
    for (int it = 0; it < 8; ++it) {
      int lb = (it * 128 + wave * 64) * 8;
      GLDS16(pA[it] + k0, &lA[lb]);
      GLDS16(pB[it] + k0, &lB[lb]);
    }
    __syncthreads();
#pragma unroll
    for (int kk = 0; kk < 2; ++kk) {
      int co = (((kk << 2) + q) ^ (fr & 7)) * 8 + fr * 64;
      bf16x8 a[4];
#pragma unroll
      for (int i = 0; i < 4; ++i)
        a[i] = *(const bf16x8*)&lA[(mb + i * 16) * 64 + co];
#pragma unroll
      for (int j = 0; j < 8; ++j) {
        bf16x8 b = *(const bf16x8*)&lB[(j * 16) * 64 + co];
#pragma unroll
        for (int i = 0; i < 4; ++i)
          acc[i][j] = __builtin_amdgcn_mfma_f32_16x16x32_bf16(a[i], b, acc[i][j], 0, 0, 0);
      }
    }
  }

#pragma unroll
  for (int i = 0; i < 4; ++i) {
#pragma unroll
    for (int reg = 0; reg < 4; ++reg) {
      int lm = mb + i * 16 + q * 4 + reg;
      if (lm < valid) {
        int tok = st[lm];
        float* op = out + (size_t)tok * 1024;
#pragma unroll
        for (int j = 0; j < 8; ++j)
          atomicAdd(&op[n0 + j * 16 + fr], acc[i][j][reg]);
      }
    }
  }
}

extern "C" void kernel_launch(void* const* d_in, const int* in_sizes, int n_in,
                              void* d_out, int out_size, void* d_ws, size_t ws_size,
                              hipStream_t stream) {
  const float* x  = (const float*)d_in[0];   // [T][D]
  const float* w  = (const float*)d_in[1];   // [T][K]
  const int*  idx = (const int*)d_in[2];     // [T][K]
  const float* W1 = (const float*)d_in[3];   // [E][2H][D]
  const float* W2 = (const float*)d_in[4];   // [E][D][H]
  float* out = (float*)d_out;

  char* ws = (char*)d_ws;
  unsigned short* W1b = (unsigned short*)(ws);              // 67108864 B
  unsigned short* W2b = (unsigned short*)(ws + 67108864);   // 33554432 B
  unsigned short* xb  = (unsigned short*)(ws + 100663296);  //  8388608 B
  unsigned short* act = (unsigned short*)(ws + 109051904);  // 33554432 B
  int*   rows = (int*)(ws + 142606336);                     //    32768 B
  float* wv   = (float*)(ws + 142639104);                   //    32768 B
  int*   meta = (int*)(ws + 142671872);                     //     1088 B

  hipMemsetAsync(d_out, 0, (size_t)out_size * sizeof(float), stream);

  k_route1<<<1, 256, 0, stream>>>(idx, meta);
  k_route2<<<(NTK + 255) / 256, 256, 0, stream>>>(idx, w, meta, rows, wv);

  k_cvt<<<(T_TOK * D_DIM / 4 + 255) / 256, 256, 0, stream>>>(x, xb, T_TOK * D_DIM / 4);
  k_cvt<<<(E_EXP * 2 * H_DIM * D_DIM / 4 + 255) / 256, 256, 0, stream>>>(W1, W1b, E_EXP * 2 * H_DIM * D_DIM / 4);
  k_cvt<<<(E_EXP * D_DIM * H_DIM / 4 + 255) / 256, 256, 0, stream>>>(W2, W2b, E_EXP * D_DIM * H_DIM / 4);

  dim3 g1(MAX_TILES, H_DIM / 64);   // (80, 32)
  dim3 g2(MAX_TILES, D_DIM / 128);  // (80, 8)
  k_gemm1<<<g1, 128, 0, stream>>>(xb, W1b, meta, rows, wv, act);
  k_gemm2<<<g2, 128, 0, stream>>>(act, W2b, meta, rows, out);
}

// Round 5
// 461.924 us; speedup vs baseline: 1.3411x; 1.0784x over previous
//
#include <hip/hip_runtime.h>
#include <stdint.h>

// Problem constants
#define T_TOK 4096
#define D_DIM 1024
#define H_DIM 2048
#define E_EXP 8
#define K_TOP 2
#define NTK   (T_TOK * K_TOP)   // 8192 (token, slot) pairs
#define MAX_TILES 48            // >= 8192/256 + 8

typedef short bf16x8 __attribute__((ext_vector_type(8)));
typedef float f32x4  __attribute__((ext_vector_type(4)));

#define MINI(a, b) ((a) < (b) ? (a) : (b))

__device__ __forceinline__ unsigned short f2bf(float f) {
  unsigned u = __float_as_uint(f);
  u += 0x7fffu + ((u >> 16) & 1u);   // round-to-nearest-even
  return (unsigned short)(u >> 16);
}

// async global->LDS, 16B per lane; lds base must be wave-uniform
#define GLDS16(gp, lp)                                                        \
  __builtin_amdgcn_global_load_lds(                                           \
      (const __attribute__((address_space(1))) void*)(gp),                    \
      (__attribute__((address_space(3))) void*)(lp), 16, 0, 0)

// meta layout (ints): [0..7] counts, [8..15] offsets, [24] n_tiles,
// [32..79] tile_expert, [112..159] tile_row0, [192..239] tile_valid

// Single-block routing: histogram + prefix + tile table (M=256) + scatter.
__global__ __launch_bounds__(256) void k_route(const int* __restrict__ idx,
                                               const float* __restrict__ w,
                                               int* __restrict__ meta,
                                               int* __restrict__ rows,
                                               float* __restrict__ wv) {
  __shared__ int lc[E_EXP];
  __shared__ int lcur[E_EXP];
  int tid = threadIdx.x;
  if (tid < E_EXP) lc[tid] = 0;
  __syncthreads();
  for (int i = tid; i < NTK; i += 256) atomicAdd(&lc[idx[i] & (E_EXP - 1)], 1);
  __syncthreads();
  if (tid == 0) {
    int off = 0, nt = 0;
    for (int e = 0; e < E_EXP; ++e) {
      int c = lc[e];
      meta[0 + e] = c;
      meta[8 + e] = off;
      lcur[e] = off;
      for (int r = 0; r < c; r += 256) {
        meta[32 + nt]  = e;
        meta[112 + nt] = off + r;
        meta[192 + nt] = MINI(256, c - r);
        ++nt;
      }
      off += c;
    }
    meta[24] = nt;
  }
  __syncthreads();
  for (int i = tid; i < NTK; i += 256) {
    int e = idx[i] & (E_EXP - 1);
    int p = atomicAdd(&lcur[e], 1);
    rows[p] = i >> 1;  // K_TOP = 2
    wv[p]   = w[i];
  }
}

// One fused f32->bf16 convert over x, W1, W2 (block-partitioned ranges).
#define NX4  (T_TOK * D_DIM / 4)                 // 1048576
#define NW14 (E_EXP * 2 * H_DIM * D_DIM / 4)     // 8388608
#define NW24 (E_EXP * D_DIM * H_DIM / 4)         // 4194304
#define NCVT (NX4 + NW14 + NW24)

__global__ __launch_bounds__(256) void k_cvt3(const float* __restrict__ x,
                                              const float* __restrict__ W1,
                                              const float* __restrict__ W2,
                                              unsigned short* __restrict__ xb,
                                              unsigned short* __restrict__ W1b,
                                              unsigned short* __restrict__ W2b) {
  int gid = blockIdx.x * 256 + threadIdx.x;
  const float* src;
  unsigned short* dst;
  int i;
  if (gid < NX4) {
    src = x; dst = xb; i = gid;
  } else if (gid < NX4 + NW14) {
    src = W1; dst = W1b; i = gid - NX4;
  } else if (gid < NCVT) {
    src = W2; dst = W2b; i = gid - (NX4 + NW14);
  } else return;
  float4 v = ((const float4*)src)[i];
  ushort4 o;
  o.x = f2bf(v.x); o.y = f2bf(v.y); o.z = f2bf(v.z); o.w = f2bf(v.w);
  ((ushort4*)dst)[i] = o;
}

// GEMM1: h = Xg @ W1e^T (both strips), act = f2bf(u * silu(gate) * w_row)
// Block: 256 threads (4 waves), tile M=256 rows x 64 act-cols (u+gate).
// Wave tile 64x128 -> acc = 32 f32x4 = 128 AGPR (2 waves/SIMD). LDS 48KB.
// M=256 halves W1 logical stream vs M=128. BK=64; XOR swizzle conflict-free.
__global__ __launch_bounds__(256, 2) void k_gemm1(
    const unsigned short* __restrict__ xb,   // [T][1024] bf16
    const unsigned short* __restrict__ W1b,  // [E][4096][1024] bf16
    const int* __restrict__ meta,
    const int* __restrict__ rows,
    const float* __restrict__ wv,
    unsigned short* __restrict__ act) {      // [8192][2048] bf16
  int nt = meta[24];
  int tb = blockIdx.x;
  if (tb >= nt) return;
  int e     = meta[32 + tb];
  int r0    = meta[112 + tb];
  int valid = meta[192 + tb];
  int n0    = blockIdx.y * 64;

  __shared__ unsigned short lA[256 * 64];   // 32 KB
  __shared__ unsigned short lB1[64 * 64];   //  8 KB
  __shared__ unsigned short lB2[64 * 64];   //  8 KB
  __shared__ float sw[256];

  int tid = threadIdx.x;
  int wave = tid >> 6, lane = tid & 63;

  sw[tid] = wv[r0 + MINI(tid, valid - 1)];

  const unsigned short* w1e = W1b + (size_t)e * (4096 * 1024);

  // staging: A = 2048 chunks over 256 threads (8 each), B strips 2 each
  const unsigned short *pA[8], *pB1[2], *pB2[2];
#pragma unroll
  for (int it = 0; it < 8; ++it) {
    int c = it * 256 + tid;
    int r = c >> 3, cc = c & 7;
    int g = cc ^ (r & 7);
    int tok = rows[r0 + MINI(r, valid - 1)];
    pA[it] = xb + (size_t)tok * 1024 + g * 8;
  }
#pragma unroll
  for (int it = 0; it < 2; ++it) {
    int c = it * 256 + tid;
    int r = c >> 3, cc = c & 7;
    int g = cc ^ (r & 7);
    pB1[it] = w1e + (size_t)(n0 + r) * 1024 + g * 8;
    pB2[it] = w1e + (size_t)(2048 + n0 + r) * 1024 + g * 8;
  }

  f32x4 zero = {0.f, 0.f, 0.f, 0.f};
  f32x4 au[4][4], ag[4][4];
#pragma unroll
  for (int i = 0; i < 4; ++i)
#pragma unroll
    for (int j = 0; j < 4; ++j) { au[i][j] = zero; ag[i][j] = zero; }

  int mb = wave * 64;
  int fr = lane & 15, q = lane >> 4;

  for (int k0 = 0; k0 < 1024; k0 += 64) {
    __syncthreads();
#pragma unroll
    for (int it = 0; it < 8; ++it)
      GLDS16(pA[it] + k0, &lA[(it * 256 + wave * 64) * 8]);
#pragma unroll
    for (int it = 0; it < 2; ++it) {
      int lb = (it * 256 + wave * 64) * 8;
      GLDS16(pB1[it] + k0, &lB1[lb]);
      GLDS16(pB2[it] + k0, &lB2[lb]);
    }
    __syncthreads();
#pragma unroll
    for (int kk = 0; kk < 2; ++kk) {
      int co = (((kk << 2) + q) ^ (fr & 7)) * 8 + fr * 64;  // swizzled read
      bf16x8 a[4];
#pragma unroll
      for (int i = 0; i < 4; ++i)
        a[i] = *(const bf16x8*)&lA[(mb + i * 16) * 64 + co];
#pragma unroll
      for (int j = 0; j < 4; ++j) {
        bf16x8 bu = *(const bf16x8*)&lB1[(j * 16) * 64 + co];
        bf16x8 bg = *(const bf16x8*)&lB2[(j * 16) * 64 + co];
#pragma unroll
        for (int i = 0; i < 4; ++i) {
          au[i][j] = __builtin_amdgcn_mfma_f32_16x16x32_bf16(a[i], bu, au[i][j], 0, 0, 0);
          ag[i][j] = __builtin_amdgcn_mfma_f32_16x16x32_bf16(a[i], bg, ag[i][j], 0, 0, 0);
        }
      }
    }
  }

#pragma unroll
  for (int i = 0; i < 4; ++i) {
#pragma unroll
    for (int reg = 0; reg < 4; ++reg) {
      int lm = mb + i * 16 + q * 4 + reg;
      if (lm < valid) {
        float wrow = sw[lm];
        size_t orow = (size_t)(r0 + lm) * 2048;
#pragma unroll
        for (int j = 0; j < 4; ++j) {
          float u = au[i][j][reg];
          float g = ag[i][j][reg];
          float s = g / (1.f + __expf(-g));
          act[orow + (n0 + j * 16 + fr)] = f2bf(u * s * wrow);
        }
      }
    }
  }
}

// GEMM2: out_slot = act @ W2e^T, atomicAdd into d_out (weight pre-applied).
// Block: 256 threads, tile M=256 x N=128, wave 64x128, acc 128 regs, LDS 48KB.
__global__ __launch_bounds__(256, 2) void k_gemm2(
    const unsigned short* __restrict__ act,  // [8192][2048] bf16
    const unsigned short* __restrict__ W2b,  // [E][1024][2048] bf16
    const int* __restrict__ meta,
    const int* __restrict__ rows,
    float* __restrict__ out) {               // [4096][1024] fp32
  int nt = meta[24];
  int tb = blockIdx.x;
  if (tb >= nt) return;
  int e     = meta[32 + tb];
  int r0    = meta[112 + tb];
  int valid = meta[192 + tb];
  int n0    = blockIdx.y * 128;

  __shared__ unsigned short lA[256 * 64];   // 32 KB
  __shared__ unsigned short lB[128 * 64];   // 16 KB
  __shared__ int st[256];

  int tid = threadIdx.x;
  int wave = tid >> 6, lane = tid & 63;
  st[tid] = rows[r0 + MINI(tid, valid - 1)];

  const unsigned short* w2e = W2b + (size_t)e * (1024 * 2048);

  const unsigned short *pA[8], *pB[4];
#pragma unroll
  for (int it = 0; it < 8; ++it) {
    int c = it * 256 + tid;
    int r = c >> 3, cc = c & 7;
    int g = cc ^ (r & 7);
    pA[it] = act + (size_t)(r0 + MINI(r, valid - 1)) * 2048 + g * 8;
  }
#pragma unroll
  for (int it = 0; it < 4; ++it) {
    int c = it * 256 + tid;
    int r = c >> 3, cc = c & 7;
    int g = cc ^ (r & 7);
    pB[it] = w2e + (size_t)(n0 + r) * 2048 + g * 8;
  }

  f32x4 zero = {0.f, 0.f, 0.f, 0.f};
  f32x4 acc[4][8];
#pragma unroll
  for (int i = 0; i < 4; ++i)
#pragma unroll
    for (int j = 0; j < 8; ++j) acc[i][j] = zero;

  int mb = wave * 64;
  int fr = lane & 15, q = lane >> 4;

  for (int k0 = 0; k0 < 2048; k0 += 64) {
    __syncthreads();
#pragma unroll
    for (int it = 0; it < 8; ++it)
      GLDS16(pA[it] + k0, &lA[(it * 256 + wave * 64) * 8]);
#pragma unroll
    for (int it = 0; it < 4; ++it)
      GLDS16(pB[it] + k0, &lB[(it * 256 + wave * 64) * 8]);
    __syncthreads();
#pragma unroll
    for (int kk = 0; kk < 2; ++kk) {
      int co = (((kk << 2) + q) ^ (fr & 7)) * 8 + fr * 64;
      bf16x8 a[4];
#pragma unroll
      for (int i = 0; i < 4; ++i)
        a[i] = *(const bf16x8*)&lA[(mb + i * 16) * 64 + co];
#pragma unroll
      for (int j = 0; j < 8; ++j) {
        bf16x8 b = *(const bf16x8*)&lB[(j * 16) * 64 + co];
#pragma unroll
        for (int i = 0; i < 4; ++i)
          acc[i][j] = __builtin_amdgcn_mfma_f32_16x16x32_bf16(a[i], b, acc[i][j], 0, 0, 0);
      }
    }
  }

#pragma unroll
  for (int i = 0; i < 4; ++i) {
#pragma unroll
    for (int reg = 0; reg < 4; ++reg) {
      int lm = mb + i * 16 + q * 4 + reg;
      if (lm < valid) {
        int tok = st[lm];
        float* op = out + (size_t)tok * 1024;
#pragma unroll
        for (int j = 0; j < 8; ++j)
          atomicAdd(&op[n0 + j * 16 + fr], acc[i][j][reg]);
      }
    }
  }
}

extern "C" void kernel_launch(void* const* d_in, const int* in_sizes, int n_in,
                              void* d_out, int out_size, void* d_ws, size_t ws_size,
                              hipStream_t stream) {
  const float* x  = (const float*)d_in[0];   // [T][D]
  const float* w  = (const float*)d_in[1];   // [T][K]
  const int*  idx = (const int*)d_in[2];     // [T][K]
  const float* W1 = (const float*)d_in[3];   // [E][2H][D]
  const float* W2 = (const float*)d_in[4];   // [E][D][H]
  float* out = (float*)d_out;

  char* ws = (char*)d_ws;
  unsigned short* W1b = (unsigned short*)(ws);              // 67108864 B
  unsigned short* W2b = (unsigned short*)(ws + 67108864);   // 33554432 B
  unsigned short* xb  = (unsigned short*)(ws + 100663296);  //  8388608 B
  unsigned short* act = (unsigned short*)(ws + 109051904);  // 33554432 B
  int*   rows = (int*)(ws + 142606336);                     //    32768 B
  float* wv   = (float*)(ws + 142639104);                   //    32768 B
  int*   meta = (int*)(ws + 142671872);                     //     1088 B

  hipMemsetAsync(d_out, 0, (size_t)out_size * sizeof(float), stream);

  k_route<<<1, 256, 0, stream>>>(idx, w, meta, rows, wv);
  k_cvt3<<<(NCVT + 255) / 256, 256, 0, stream>>>(x, W1, W2, xb, W1b, W2b);

  dim3 g1(MAX_TILES, H_DIM / 64);   // (48, 32)
  dim3 g2(MAX_TILES, D_DIM / 128);  // (48, 8)
  k_gemm1<<<g1, 256, 0, stream>>>(xb, W1b, meta, rows, wv, act);
  k_gemm2<<<g2, 256, 0, stream>>>(act, W2b, meta, rows, out);
}